// Round 5
// baseline (202.397 us; speedup 1.0000x reference)
//
#include <hip/hip_runtime.h>
#include <math.h>

#define H_BINS 61
#define HB2 (H_BINS * H_BINS)       // 3721
#define SLOTS (3 * HB2)             // 11163 floats per partial
#define SLOTS_PAD 11164             // padded to /4 for float4 flush
#define NPIX 22500                  // 150*150
#define NIMG 64
#define CH 4                        // chunks per image (fused path)
#define PPC (NPIX / CH)             // 5625
#define NT 1024                     // threads per block (fused path)
#define OUT_ELEMS (NIMG * SLOTS)

// EPS from reference, as float32
#define EPSF 2.2204e-16f
// EPS_BIN/2 = 6.4/61/2 computed in double, cast to f32
#define HALFW ((float)(6.4 / 61.0 / 2.0))

// A[h] = -3.2f + h * delta, all f32 rn ops (mirrors linspace in f32; rn blocks FMA)
__device__ __forceinline__ float bin_center(int h) {
    const float delta = __fdiv_rn(__fsub_rn(3.0951f, -3.2f), 60.0f);
    return __fadd_rn(-3.2f, __fmul_rn((float)h, delta));
}

// All bins h with |t - A[h]| <= HALFW (exact f32 predicate); 0..2 matches.
__device__ __forceinline__ int find_bins(float t, int* out) {
    const float inv_delta = 60.0f / 6.2951f;  // index ESTIMATE only
    int h0 = (int)floorf(__fmul_rn(__fadd_rn(t, 3.2f), inv_delta) + 0.5f);
    int c = 0;
    #pragma unroll
    for (int dh = -1; dh <= 1; ++dh) {
        int h = h0 + dh;
        if (h < 0 || h >= H_BINS) continue;
        float a = bin_center(h);
        if (fabsf(__fsub_rn(t, a)) <= HALFW) {
            if (c < 2) out[c] = h;
            ++c;
        }
    }
    return c < 2 ? c : 2;
}

// Per-pixel core: identical ops to all passing rounds.
__device__ __forceinline__ void process_pixel(const float* __restrict__ Xb, int n,
                                              float (*hist)[HB2]) {
    float r  = Xb[n];
    float g  = Xb[NPIX + n];
    float bl = Xb[2 * NPIX + n];

    float iy = __fsqrt_rn(__fadd_rn(
        __fadd_rn(__fmul_rn(r, r), __fmul_rn(g, g)), __fmul_rn(bl, bl)));

    float l0 = logf(__fadd_rn(fabsf(r),  EPSF));
    float l1 = logf(__fadd_rn(fabsf(g),  EPSF));
    float l2 = logf(__fadd_rn(fabsf(bl), EPSF));

    float iu[3], iv[3];
    iu[0] = __fsub_rn(l0, l1);  iv[0] = __fsub_rn(l0, l2);
    iu[1] = __fsub_rn(l1, l0);  iv[1] = __fsub_rn(l1, l2);
    iu[2] = __fsub_rn(l2, l0);  iv[2] = __fsub_rn(l2, l1);

    #pragma unroll
    for (int p = 0; p < 3; ++p) {
        int bu[2], bv[2];
        int nu = find_bins(iu[p], bu);
        if (nu == 0) continue;
        int nv = find_bins(iv[p], bv);
        if (nv == 0) continue;
        for (int a = 0; a < nu; ++a)
            for (int c = 0; c < nv; ++c)
                unsafeAtomicAdd(&hist[p][bu[a] * H_BINS + bv[c]], iy);  // ds_add_f32
    }
}

// Fused: 256 blocks = 64 images x 4 chunks. Partial -> ws (float4 stores);
// last block per image (device-scope counter) reduces 4 partials + finalizes.
__global__ __launch_bounds__(NT) void hist_fused(const float* __restrict__ X,
                                                 float* __restrict__ wsdata,
                                                 int* __restrict__ cnt,
                                                 const float* __restrict__ C,
                                                 float* __restrict__ out) {
    __shared__ float hist[3][HB2];
    __shared__ float pad[1];          // makes flush region 11164 floats
    __shared__ int s_old;
    const int chunk = blockIdx.x % CH;
    const int b     = blockIdx.x / CH;

    float* hflat = &hist[0][0];
    for (int i = threadIdx.x; i < SLOTS; i += NT) hflat[i] = 0.0f;
    if (threadIdx.x == 0) pad[0] = 0.0f;
    __syncthreads();

    const float* Xb = X + (size_t)b * 3 * NPIX;
    const int n0 = chunk * PPC;
    const int n1 = n0 + PPC;
    for (int n = n0 + threadIdx.x; n < n1; n += NT)
        process_pixel(Xb, n, hist);
    __syncthreads();

    // flush partial: coalesced float4 streaming stores (no atomics)
    {
        const float4* src = (const float4*)hflat;              // LDS is 16B aligned
        float4* dst = (float4*)(wsdata + (size_t)blockIdx.x * SLOTS_PAD);
        for (int i = threadIdx.x; i < SLOTS_PAD / 4; i += NT) dst[i] = src[i];
    }

    __threadfence();                   // make partial visible device-wide
    __syncthreads();
    if (threadIdx.x == 0) s_old = atomicAdd(&cnt[b], 1);   // device-scope
    __syncthreads();
    if (s_old != CH - 1) return;

    // last block of image b: reduce 4 partials, sqrt*C/N, write final out
    __threadfence();                   // acquire: see other blocks' partials
    const float* p0 = wsdata + (size_t)(b * CH + 0) * SLOTS_PAD;
    const float* p1 = wsdata + (size_t)(b * CH + 1) * SLOTS_PAD;
    const float* p2 = wsdata + (size_t)(b * CH + 2) * SLOTS_PAD;
    const float* p3 = wsdata + (size_t)(b * CH + 3) * SLOTS_PAD;
    float sc0 = __fdiv_rn(C[0], 22500.0f);
    float sc1 = __fdiv_rn(C[1], 22500.0f);
    float sc2 = __fdiv_rn(C[2], 22500.0f);
    float* ob = out + (size_t)b * SLOTS;
    for (int j = threadIdx.x; j < SLOTS; j += NT) {
        float s = __fadd_rn(__fadd_rn(__fadd_rn(p0[j], p1[j]), p2[j]), p3[j]);
        float scale = (j < HB2) ? sc0 : ((j < 2 * HB2) ? sc1 : sc2);
        ob[j] = __fmul_rn(__fsqrt_rn(s), scale);
    }
}

// ---- tiny-ws fallback: accumulate into out with device atomics ----
__global__ __launch_bounds__(256) void zero_kernel(float4* __restrict__ o, int n4) {
    int i = blockIdx.x * 256 + threadIdx.x;
    if (i < n4) o[i] = make_float4(0.f, 0.f, 0.f, 0.f);
}
__global__ __launch_bounds__(512) void hist_atomic(const float* __restrict__ X,
                                                   float* __restrict__ out) {
    __shared__ float hist[3][HB2];
    const int chunk = blockIdx.x % 12;
    const int b     = blockIdx.x / 12;
    float* hflat = &hist[0][0];
    for (int i = threadIdx.x; i < SLOTS; i += 512) hflat[i] = 0.0f;
    __syncthreads();
    const float* Xb = X + (size_t)b * 3 * NPIX;
    const int ppc = NPIX / 12;
    for (int n = chunk * ppc + threadIdx.x; n < (chunk + 1) * ppc; n += 512)
        process_pixel(Xb, n, hist);
    __syncthreads();
    float* ob = out + (size_t)b * SLOTS;
    for (int i = threadIdx.x; i < SLOTS; i += 512) {
        float v = hflat[i];
        if (v != 0.0f) unsafeAtomicAdd(&ob[i], v);
    }
}
__global__ __launch_bounds__(256) void finalize_kernel(float* __restrict__ out,
                                                       const float* __restrict__ C) {
    int idx = blockIdx.x * 256 + threadIdx.x;
    if (idx >= OUT_ELEMS) return;
    int ch = (idx / HB2) % 3;
    float scale = __fdiv_rn(C[ch], 22500.0f);
    out[idx] = __fmul_rn(__fsqrt_rn(out[idx]), scale);
}

extern "C" void kernel_launch(void* const* d_in, const int* in_sizes, int n_in,
                              void* d_out, int out_size, void* d_ws, size_t ws_size,
                              hipStream_t stream) {
    const float* X = (const float*)d_in[0];
    const float* C = (const float*)d_in[1];
    float* out = (float*)d_out;

    // ws layout: [0,256) bytes = 64 int counters; partials after (256B aligned)
    size_t need = 256 + (size_t)NIMG * CH * SLOTS_PAD * sizeof(float);  // ~11.4 MB
    if (ws_size >= need) {
        int*   cnt    = (int*)d_ws;
        float* wsdata = (float*)((char*)d_ws + 256);
        hipMemsetAsync(cnt, 0, 64 * sizeof(int), stream);   // zero counters each call
        hist_fused<<<NIMG * CH, NT, 0, stream>>>(X, wsdata, cnt, C, out);
    } else {
        int n4 = OUT_ELEMS / 4;
        zero_kernel<<<(n4 + 255) / 256, 256, 0, stream>>>((float4*)out, n4);
        hist_atomic<<<NIMG * 12, 512, 0, stream>>>(X, out);
        finalize_kernel<<<(OUT_ELEMS + 255) / 256, 256, 0, stream>>>(out, C);
    }
}

// Round 6
// 48.516 us; speedup vs baseline: 4.1718x; 4.1718x over previous
//
#include <hip/hip_runtime.h>
#include <math.h>

#define H_BINS 61
#define HB2 (H_BINS * H_BINS)       // 3721
#define SLOTS (3 * HB2)             // 11163 floats per partial
#define SLOTS_PAD 11164             // padded to /4 for float4 flush
#define NPIX 22500                  // 150*150
#define NIMG 64
#define CH 9                        // chunks per image: 2500 px = 625 float4 quads exact
#define QPC 625                     // quads per chunk
#define NT 512
#define OUT_ELEMS (NIMG * SLOTS)
#define QPI (SLOTS_PAD / 4)         // 2791 output quads per image

// EPS from reference, as float32
#define EPSF 2.2204e-16f
// EPS_BIN/2 = 6.4/61/2 computed in double, cast to f32
#define HALFW ((float)(6.4 / 61.0 / 2.0))

// A[h] = -3.2f + h * delta, all f32 rn ops (mirrors linspace in f32; rn blocks FMA)
__device__ __forceinline__ float bin_center(int h) {
    const float delta = __fdiv_rn(__fsub_rn(3.0951f, -3.2f), 60.0f);
    return __fadd_rn(-3.2f, __fmul_rn((float)h, delta));
}

// All bins h with |t - A[h]| <= HALFW (exact f32 predicate); 0..2 matches.
__device__ __forceinline__ int find_bins(float t, int* out) {
    const float inv_delta = 60.0f / 6.2951f;  // index ESTIMATE only
    int h0 = (int)floorf(__fmul_rn(__fadd_rn(t, 3.2f), inv_delta) + 0.5f);
    int c = 0;
    #pragma unroll
    for (int dh = -1; dh <= 1; ++dh) {
        int h = h0 + dh;
        if (h < 0 || h >= H_BINS) continue;
        float a = bin_center(h);
        if (fabsf(__fsub_rn(t, a)) <= HALFW) {
            if (c < 2) out[c] = h;
            ++c;
        }
    }
    return c < 2 ? c : 2;
}

// One block = (image, quad-chunk). Pixel body INLINED, direct __shared__ access
// (R5 lesson: generic-pointer helper + NT=1024 => VGPR 12, all-scratch, 5x slow).
// float4 loads give 4 independent per-pixel chains per thread (ILP).
__global__ __launch_bounds__(NT) void hist_kernel(const float* __restrict__ X,
                                                  float* __restrict__ ws) {
    __shared__ float hflat[SLOTS_PAD];
    const int chunk = blockIdx.x % CH;
    const int b     = blockIdx.x / CH;

    for (int i = threadIdx.x; i < SLOTS_PAD; i += NT) hflat[i] = 0.0f;
    __syncthreads();

    const float* Xb = X + (size_t)b * 3 * NPIX;   // 67500*b: float4-aligned
    const int q0 = chunk * QPC;

    for (int q = q0 + threadIdx.x; q < q0 + QPC; q += NT) {
        float4 r4 = *(const float4*)(Xb + 4 * q);
        float4 g4 = *(const float4*)(Xb + NPIX + 4 * q);
        float4 b4 = *(const float4*)(Xb + 2 * NPIX + 4 * q);
        float rr[4] = {r4.x, r4.y, r4.z, r4.w};
        float gg[4] = {g4.x, g4.y, g4.z, g4.w};
        float bb[4] = {b4.x, b4.y, b4.z, b4.w};

        #pragma unroll
        for (int k = 0; k < 4; ++k) {
            float r = rr[k], g = gg[k], bl = bb[k];

            // Iy = sqrt(r*r+g*g+b*b), f32 rn ops, sum order ((rr+gg)+bb)
            float iy = __fsqrt_rn(__fadd_rn(
                __fadd_rn(__fmul_rn(r, r), __fmul_rn(g, g)), __fmul_rn(bl, bl)));

            // logf(|x| + EPS) in f32 — identical to reference ops
            float l0 = logf(__fadd_rn(fabsf(r),  EPSF));
            float l1 = logf(__fadd_rn(fabsf(g),  EPSF));
            float l2 = logf(__fadd_rn(fabsf(bl), EPSF));

            // pairs: (i,u,v) = (0,1,2), (1,0,2), (2,0,1)
            float iu[3], iv[3];
            iu[0] = __fsub_rn(l0, l1);  iv[0] = __fsub_rn(l0, l2);
            iu[1] = __fsub_rn(l1, l0);  iv[1] = __fsub_rn(l1, l2);
            iu[2] = __fsub_rn(l2, l0);  iv[2] = __fsub_rn(l2, l1);

            #pragma unroll
            for (int p = 0; p < 3; ++p) {
                int bu[2], bv[2];
                int nu = find_bins(iu[p], bu);
                if (nu == 0) continue;
                int nv = find_bins(iv[p], bv);
                if (nv == 0) continue;
                for (int a = 0; a < nu; ++a)
                    for (int c = 0; c < nv; ++c)
                        unsafeAtomicAdd(&hflat[p * HB2 + bu[a] * H_BINS + bv[c]], iy);
            }
        }
    }
    __syncthreads();

    // flush private partial: coalesced float4 streaming stores, zero atomics
    float4* dst = (float4*)(ws + (size_t)blockIdx.x * SLOTS_PAD);
    const float4* src = (const float4*)hflat;
    for (int i = threadIdx.x; i < SLOTS_PAD / 4; i += NT) dst[i] = src[i];
}

// out = sqrt(sum of 9 chunk-partials) * C[ch]/N, float4-vectorized
__global__ __launch_bounds__(256) void reduce_kernel(const float* __restrict__ ws,
                                                     const float* __restrict__ C,
                                                     float* __restrict__ out) {
    int t = blockIdx.x * 256 + threadIdx.x;
    if (t >= NIMG * QPI) return;
    int b  = t / QPI;
    int j  = (t % QPI) * 4;
    const float* base = ws + (size_t)b * CH * SLOTS_PAD + j;

    float4 s = *(const float4*)base;
    #pragma unroll
    for (int c = 1; c < CH; ++c) {
        float4 v = *(const float4*)(base + (size_t)c * SLOTS_PAD);
        s.x = __fadd_rn(s.x, v.x); s.y = __fadd_rn(s.y, v.y);
        s.z = __fadd_rn(s.z, v.z); s.w = __fadd_rn(s.w, v.w);
    }
    float sv[4] = {s.x, s.y, s.z, s.w};
    float* ob = out + (size_t)b * SLOTS;
    #pragma unroll
    for (int k = 0; k < 4; ++k) {
        int jj = j + k;
        if (jj >= SLOTS) break;                       // pad element: don't store
        int ch = jj / HB2;
        float scale = __fdiv_rn(C[ch], 22500.0f);     // C[i]/N in f32
        ob[jj] = __fmul_rn(__fsqrt_rn(sv[k]), scale);
    }
}

// ---- tiny-ws fallback (never taken with 256MB ws; kept for safety) ----
__global__ __launch_bounds__(256) void zero_kernel(float4* __restrict__ o, int n4) {
    int i = blockIdx.x * 256 + threadIdx.x;
    if (i < n4) o[i] = make_float4(0.f, 0.f, 0.f, 0.f);
}
__global__ __launch_bounds__(512) void hist_atomic(const float* __restrict__ X,
                                                   float* __restrict__ out) {
    __shared__ float hflat[SLOTS];
    const int chunk = blockIdx.x % 12;
    const int b     = blockIdx.x / 12;
    for (int i = threadIdx.x; i < SLOTS; i += 512) hflat[i] = 0.0f;
    __syncthreads();
    const float* Xb = X + (size_t)b * 3 * NPIX;
    const int ppc = NPIX / 12;
    for (int n = chunk * ppc + threadIdx.x; n < (chunk + 1) * ppc; n += 512) {
        float r = Xb[n], g = Xb[NPIX + n], bl = Xb[2 * NPIX + n];
        float iy = __fsqrt_rn(__fadd_rn(
            __fadd_rn(__fmul_rn(r, r), __fmul_rn(g, g)), __fmul_rn(bl, bl)));
        float l0 = logf(__fadd_rn(fabsf(r),  EPSF));
        float l1 = logf(__fadd_rn(fabsf(g),  EPSF));
        float l2 = logf(__fadd_rn(fabsf(bl), EPSF));
        float iu[3], iv[3];
        iu[0] = __fsub_rn(l0, l1);  iv[0] = __fsub_rn(l0, l2);
        iu[1] = __fsub_rn(l1, l0);  iv[1] = __fsub_rn(l1, l2);
        iu[2] = __fsub_rn(l2, l0);  iv[2] = __fsub_rn(l2, l1);
        #pragma unroll
        for (int p = 0; p < 3; ++p) {
            int bu[2], bv[2];
            int nu = find_bins(iu[p], bu); if (nu == 0) continue;
            int nv = find_bins(iv[p], bv); if (nv == 0) continue;
            for (int a = 0; a < nu; ++a)
                for (int c = 0; c < nv; ++c)
                    unsafeAtomicAdd(&hflat[p * HB2 + bu[a] * H_BINS + bv[c]], iy);
        }
    }
    __syncthreads();
    float* ob = out + (size_t)b * SLOTS;
    for (int i = threadIdx.x; i < SLOTS; i += 512) {
        float v = hflat[i];
        if (v != 0.0f) unsafeAtomicAdd(&ob[i], v);
    }
}
__global__ __launch_bounds__(256) void finalize_kernel(float* __restrict__ out,
                                                       const float* __restrict__ C) {
    int idx = blockIdx.x * 256 + threadIdx.x;
    if (idx >= OUT_ELEMS) return;
    int ch = (idx / HB2) % 3;
    float scale = __fdiv_rn(C[ch], 22500.0f);
    out[idx] = __fmul_rn(__fsqrt_rn(out[idx]), scale);
}

extern "C" void kernel_launch(void* const* d_in, const int* in_sizes, int n_in,
                              void* d_out, int out_size, void* d_ws, size_t ws_size,
                              hipStream_t stream) {
    const float* X = (const float*)d_in[0];
    const float* C = (const float*)d_in[1];
    float* out = (float*)d_out;
    float* ws  = (float*)d_ws;

    size_t need = (size_t)NIMG * CH * SLOTS_PAD * sizeof(float);  // ~25.7 MB
    if (ws_size >= need) {
        hist_kernel<<<NIMG * CH, NT, 0, stream>>>(X, ws);
        int rt = NIMG * QPI;
        reduce_kernel<<<(rt + 255) / 256, 256, 0, stream>>>(ws, C, out);
    } else {
        int n4 = OUT_ELEMS / 4;
        zero_kernel<<<(n4 + 255) / 256, 256, 0, stream>>>((float4*)out, n4);
        hist_atomic<<<NIMG * 12, 512, 0, stream>>>(X, out);
        finalize_kernel<<<(OUT_ELEMS + 255) / 256, 256, 0, stream>>>(out, C);
    }
}

// Round 7
// 46.271 us; speedup vs baseline: 4.3742x; 1.0485x over previous
//
#include <hip/hip_runtime.h>
#include <math.h>

#define H_BINS 61
#define HB2 (H_BINS * H_BINS)       // 3721
#define SLOTS (3 * HB2)             // 11163 floats per partial
#define SLOTS_PAD 11164             // /4 for float4 flush
#define NPIX 22500                  // 150*150
#define NIMG 64
#define CH 9                        // 2500 px = 625 float4 quads exactly
#define QPC 625
#define NT 512
#define OUT_ELEMS (NIMG * SLOTS)
#define QPI (SLOTS_PAD / 4)         // 2791

// EPS from reference, as float32
#define EPSF 2.2204e-16f
// EPS_BIN/2 = 6.4/61/2 in double, cast to f32
#define HALFW ((float)(6.4 / 61.0 / 2.0))

// A[h] = -3.2f + h*delta, all f32 rn ops (mirrors linspace in f32; rn blocks FMA)
__device__ __forceinline__ float bin_center(int h) {
    const float delta = __fdiv_rn(__fsub_rn(3.0951f, -3.2f), 60.0f);
    return __fadd_rn(-3.2f, __fmul_rn((float)h, delta));
}

// Single matching bin (or -1). Branchless, NO arrays (scratch-free; R6 lesson:
// runtime-indexed out[c] forced private-segment traffic, ~200cyc/access).
// Disjointness proof (f32): 2*HALFW = 0.10491803 < A[h+1]-A[h] = 0.1049183,
// margin 3e-7 >> f32 rounding of the predicate => at most one h matches.
__device__ __forceinline__ int find_bin(float t) {
    const float inv_delta = 60.0f / 6.2951f;   // index ESTIMATE only
    int h0 = (int)floorf(__fmul_rn(__fadd_rn(t, 3.2f), inv_delta) + 0.5f);
    int best = -1;
    #pragma unroll
    for (int dh = -1; dh <= 1; ++dh) {
        int h = h0 + dh;
        bool in_rng = ((unsigned)h < (unsigned)H_BINS);
        bool hit = (fabsf(__fsub_rn(t, bin_center(h))) <= HALFW);
        best = (in_rng && hit) ? h : best;     // v_cndmask
    }
    return best;
}

// Per-pixel pair scatter, array-free.
#define DO_PAIR(P, IU, IV)                                                   \
    {                                                                        \
        int bu_ = find_bin(IU);                                              \
        int bv_ = find_bin(IV);                                              \
        if (bu_ >= 0 && bv_ >= 0)                                            \
            unsafeAtomicAdd(&hflat[(P) * HB2 + bu_ * H_BINS + bv_], iy);     \
    }

#define DO_PIXEL(r, g, bl)                                                   \
    {                                                                        \
        float iy = __fsqrt_rn(__fadd_rn(                                     \
            __fadd_rn(__fmul_rn(r, r), __fmul_rn(g, g)), __fmul_rn(bl, bl)));\
        float l0 = logf(__fadd_rn(fabsf(r),  EPSF));                         \
        float l1 = logf(__fadd_rn(fabsf(g),  EPSF));                         \
        float l2 = logf(__fadd_rn(fabsf(bl), EPSF));                         \
        float d01 = __fsub_rn(l0, l1);                                       \
        float d02 = __fsub_rn(l0, l2);                                       \
        float d12 = __fsub_rn(l1, l2);                                       \
        float d10 = __fsub_rn(l1, l0);                                       \
        float d20 = __fsub_rn(l2, l0);                                       \
        float d21 = __fsub_rn(l2, l1);                                       \
        DO_PAIR(0, d01, d02)                                                 \
        DO_PAIR(1, d10, d12)                                                 \
        DO_PAIR(2, d20, d21)                                                 \
    }

// One block = (image, quad-chunk). Body inlined, direct __shared__ access.
__global__ __launch_bounds__(NT) void hist_kernel(const float* __restrict__ X,
                                                  float* __restrict__ ws) {
    __shared__ float hflat[SLOTS_PAD];
    const int chunk = blockIdx.x % CH;
    const int b     = blockIdx.x / CH;

    {   // vectorized zero-init
        float4* h4 = (float4*)hflat;
        float4 z = make_float4(0.f, 0.f, 0.f, 0.f);
        for (int i = threadIdx.x; i < SLOTS_PAD / 4; i += NT) h4[i] = z;
    }
    __syncthreads();

    const float* Xb = X + (size_t)b * 3 * NPIX;   // float4-aligned (67500*b)
    const int q0 = chunk * QPC;

    for (int q = q0 + threadIdx.x; q < q0 + QPC; q += NT) {
        float4 r4 = *(const float4*)(Xb + 4 * q);
        float4 g4 = *(const float4*)(Xb + NPIX + 4 * q);
        float4 b4 = *(const float4*)(Xb + 2 * NPIX + 4 * q);
        DO_PIXEL(r4.x, g4.x, b4.x)
        DO_PIXEL(r4.y, g4.y, b4.y)
        DO_PIXEL(r4.z, g4.z, b4.z)
        DO_PIXEL(r4.w, g4.w, b4.w)
    }
    __syncthreads();

    // flush private partial: coalesced float4 stores, zero atomics
    float4* dst = (float4*)(ws + (size_t)blockIdx.x * SLOTS_PAD);
    const float4* src = (const float4*)hflat;
    for (int i = threadIdx.x; i < SLOTS_PAD / 4; i += NT) dst[i] = src[i];
}

// out = sqrt(sum of 9 chunk-partials) * C[ch]/N, float4-vectorized
__global__ __launch_bounds__(256) void reduce_kernel(const float* __restrict__ ws,
                                                     const float* __restrict__ C,
                                                     float* __restrict__ out) {
    int t = blockIdx.x * 256 + threadIdx.x;
    if (t >= NIMG * QPI) return;
    int b = t / QPI;
    int j = (t % QPI) * 4;
    const float* base = ws + (size_t)b * CH * SLOTS_PAD + j;

    float4 s = *(const float4*)base;
    #pragma unroll
    for (int c = 1; c < CH; ++c) {
        float4 v = *(const float4*)(base + (size_t)c * SLOTS_PAD);
        s.x = __fadd_rn(s.x, v.x); s.y = __fadd_rn(s.y, v.y);
        s.z = __fadd_rn(s.z, v.z); s.w = __fadd_rn(s.w, v.w);
    }
    float* ob = out + (size_t)b * SLOTS;
    // unrolled, static indices only
    int ch0 = j / HB2;            // channel may change within the quad
    #pragma unroll
    for (int k = 0; k < 4; ++k) {
        int jj = j + k;
        if (jj >= SLOTS) break;
        int ch = (k == 0) ? ch0 : jj / HB2;
        float sv = (k == 0) ? s.x : (k == 1) ? s.y : (k == 2) ? s.z : s.w;
        float scale = __fdiv_rn(C[ch], 22500.0f);   // C[i]/N in f32
        ob[jj] = __fmul_rn(__fsqrt_rn(sv), scale);
    }
}

// ---- tiny-ws fallback (not taken with 256MB ws) ----
__global__ __launch_bounds__(256) void zero_kernel(float4* __restrict__ o, int n4) {
    int i = blockIdx.x * 256 + threadIdx.x;
    if (i < n4) o[i] = make_float4(0.f, 0.f, 0.f, 0.f);
}
__global__ __launch_bounds__(512) void hist_atomic(const float* __restrict__ X,
                                                   float* __restrict__ out) {
    __shared__ float hflat[SLOTS];
    const int chunk = blockIdx.x % 12;
    const int b     = blockIdx.x / 12;
    for (int i = threadIdx.x; i < SLOTS; i += 512) hflat[i] = 0.0f;
    __syncthreads();
    const float* Xb = X + (size_t)b * 3 * NPIX;
    const int ppc = NPIX / 12;
    for (int n = chunk * ppc + threadIdx.x; n < (chunk + 1) * ppc; n += 512) {
        float r = Xb[n], g = Xb[NPIX + n], bl = Xb[2 * NPIX + n];
        DO_PIXEL(r, g, bl)
    }
    __syncthreads();
    float* ob = out + (size_t)b * SLOTS;
    for (int i = threadIdx.x; i < SLOTS; i += 512) {
        float v = hflat[i];
        if (v != 0.0f) unsafeAtomicAdd(&ob[i], v);
    }
}
__global__ __launch_bounds__(256) void finalize_kernel(float* __restrict__ out,
                                                       const float* __restrict__ C) {
    int idx = blockIdx.x * 256 + threadIdx.x;
    if (idx >= OUT_ELEMS) return;
    int ch = (idx / HB2) % 3;
    float scale = __fdiv_rn(C[ch], 22500.0f);
    out[idx] = __fmul_rn(__fsqrt_rn(out[idx]), scale);
}

extern "C" void kernel_launch(void* const* d_in, const int* in_sizes, int n_in,
                              void* d_out, int out_size, void* d_ws, size_t ws_size,
                              hipStream_t stream) {
    const float* X = (const float*)d_in[0];
    const float* C = (const float*)d_in[1];
    float* out = (float*)d_out;
    float* ws  = (float*)d_ws;

    size_t need = (size_t)NIMG * CH * SLOTS_PAD * sizeof(float);  // ~25.7 MB
    if (ws_size >= need) {
        hist_kernel<<<NIMG * CH, NT, 0, stream>>>(X, ws);
        int rt = NIMG * QPI;
        reduce_kernel<<<(rt + 255) / 256, 256, 0, stream>>>(ws, C, out);
    } else {
        int n4 = OUT_ELEMS / 4;
        zero_kernel<<<(n4 + 255) / 256, 256, 0, stream>>>((float4*)out, n4);
        hist_atomic<<<NIMG * 12, 512, 0, stream>>>(X, out);
        finalize_kernel<<<(OUT_ELEMS + 255) / 256, 256, 0, stream>>>(out, C);
    }
}

// Round 8
// 45.813 us; speedup vs baseline: 4.4179x; 1.0100x over previous
//
#include <hip/hip_runtime.h>
#include <math.h>

#define H_BINS 61
#define HB2 (H_BINS * H_BINS)       // 3721
#define SLOTS (3 * HB2)             // 11163 floats per partial
#define SLOTS_PAD 11164             // /4 for float4 flush
#define NPIX 22500                  // 150*150
#define NIMG 64
#define CH 9                        // 9 chunks x 625 quads = 5625 quads/image
#define QPC 625
#define NT 640                      // 1 quad per thread (625 active), 10 waves
#define OUT_ELEMS (NIMG * SLOTS)
#define QPI (SLOTS_PAD / 4)         // 2791 quads per partial

// EPS from reference, as float32
#define EPSF 2.2204e-16f
// EPS_BIN/2 = 6.4/61/2 in double, cast to f32
#define HALFW ((float)(6.4 / 61.0 / 2.0))

// A[h] = -3.2f + h*delta, all f32 rn ops (mirrors linspace in f32; rn blocks FMA)
__device__ __forceinline__ float bin_center(int h) {
    const float delta = __fdiv_rn(__fsub_rn(3.0951f, -3.2f), 60.0f);
    return __fadd_rn(-3.2f, __fmul_rn((float)h, delta));
}

// Single matching bin (or -1), branchless, array-free, 2 candidates.
// Proof: scaled s_true=(t+3.2)/delta lies in [h-0.5, h+0.5] for a match;
// |s_est - s_true| <= ~2e-5 << 0.5, so h ∈ {floor(s_est), floor(s_est)+1}.
// The exact f32 predicate below decides; estimate only selects candidates.
__device__ __forceinline__ int find_bin(float t) {
    const float inv_delta = 60.0f / 6.2951f;   // estimate only
    int k = (int)floorf(__fmul_rn(__fadd_rn(t, 3.2f), inv_delta));
    int best = -1;
    #pragma unroll
    for (int dh = 0; dh <= 1; ++dh) {
        int h = k + dh;
        bool in_rng = ((unsigned)h < (unsigned)H_BINS);
        bool hit = (fabsf(__fsub_rn(t, bin_center(h))) <= HALFW);
        best = (in_rng && hit) ? h : best;     // v_cndmask
    }
    return best;
}

#define DO_PAIR(P, IU, IV)                                                   \
    {                                                                        \
        int bu_ = find_bin(IU);                                              \
        int bv_ = find_bin(IV);                                              \
        if (bu_ >= 0 && bv_ >= 0)                                            \
            unsafeAtomicAdd(&hflat[(P) * HB2 + bu_ * H_BINS + bv_], iy);     \
    }

#define DO_PIXEL(r, g, bl)                                                   \
    {                                                                        \
        float iy = __fsqrt_rn(__fadd_rn(                                     \
            __fadd_rn(__fmul_rn(r, r), __fmul_rn(g, g)), __fmul_rn(bl, bl)));\
        float l0 = logf(__fadd_rn(fabsf(r),  EPSF));                         \
        float l1 = logf(__fadd_rn(fabsf(g),  EPSF));                         \
        float l2 = logf(__fadd_rn(fabsf(bl), EPSF));                         \
        float d01 = __fsub_rn(l0, l1);                                       \
        float d02 = __fsub_rn(l0, l2);                                       \
        float d12 = __fsub_rn(l1, l2);                                       \
        float d10 = __fsub_rn(l1, l0);                                       \
        float d20 = __fsub_rn(l2, l0);                                       \
        float d21 = __fsub_rn(l2, l1);                                       \
        DO_PAIR(0, d01, d02)                                                 \
        DO_PAIR(1, d10, d12)                                                 \
        DO_PAIR(2, d20, d21)                                                 \
    }

// bid = c*64 + b  =>  XCD(bid) = bid%8 = b%8: all 9 partials of image b are
// written through ONE XCD's L2 (402 KB/image << 4 MB), and the matching
// reduce block (blockIdx=b, 64-block grid => XCD b%8) reads them L2-hot.
__global__ __launch_bounds__(NT) void hist_kernel(const float* __restrict__ X,
                                                  float* __restrict__ ws) {
    __shared__ float hflat[SLOTS_PAD];
    const int bid = blockIdx.x;
    const int b   = bid & 63;      // image
    const int c   = bid >> 6;      // chunk 0..8

    {   // vectorized zero-init
        float4* h4 = (float4*)hflat;
        float4 z = make_float4(0.f, 0.f, 0.f, 0.f);
        for (int i = threadIdx.x; i < SLOTS_PAD / 4; i += NT) h4[i] = z;
    }
    __syncthreads();

    if (threadIdx.x < QPC) {       // exactly one quad per thread: no tail loop
        const float* Xb = X + (size_t)b * 3 * NPIX;   // float4-aligned
        const int q = c * QPC + threadIdx.x;
        float4 r4 = *(const float4*)(Xb + 4 * q);
        float4 g4 = *(const float4*)(Xb + NPIX + 4 * q);
        float4 b4 = *(const float4*)(Xb + 2 * NPIX + 4 * q);
        DO_PIXEL(r4.x, g4.x, b4.x)
        DO_PIXEL(r4.y, g4.y, b4.y)
        DO_PIXEL(r4.z, g4.z, b4.z)
        DO_PIXEL(r4.w, g4.w, b4.w)
    }
    __syncthreads();

    // flush private partial: coalesced float4 stores (absorbed by local L2)
    float4* dst = (float4*)(ws + (size_t)bid * SLOTS_PAD);
    const float4* src = (const float4*)hflat;
    for (int i = threadIdx.x; i < SLOTS_PAD / 4; i += NT) dst[i] = src[i];
}

// One block per image (grid=64 => block b on XCD b%8, matching its partials).
__global__ __launch_bounds__(1024) void reduce_kernel(const float* __restrict__ ws,
                                                      const float* __restrict__ C,
                                                      float* __restrict__ out) {
    const int b = blockIdx.x;
    float sc0 = __fdiv_rn(C[0], 22500.0f);
    float sc1 = __fdiv_rn(C[1], 22500.0f);
    float sc2 = __fdiv_rn(C[2], 22500.0f);
    const float* base0 = ws + (size_t)b * SLOTS_PAD;
    float* ob = out + (size_t)b * SLOTS;

    for (int t = threadIdx.x; t < QPI; t += 1024) {
        int j = t * 4;
        const float* base = base0 + j;
        float4 s = *(const float4*)base;
        #pragma unroll
        for (int c = 1; c < CH; ++c) {
            float4 v = *(const float4*)(base + (size_t)c * 64 * SLOTS_PAD);
            s.x = __fadd_rn(s.x, v.x); s.y = __fadd_rn(s.y, v.y);
            s.z = __fadd_rn(s.z, v.z); s.w = __fadd_rn(s.w, v.w);
        }
        #pragma unroll
        for (int k = 0; k < 4; ++k) {
            int jj = j + k;
            if (jj >= SLOTS) break;                 // pad element
            int ch = jj / HB2;
            float sv = (k == 0) ? s.x : (k == 1) ? s.y : (k == 2) ? s.z : s.w;
            float scale = (ch == 0) ? sc0 : (ch == 1) ? sc1 : sc2;
            ob[jj] = __fmul_rn(__fsqrt_rn(sv), scale);
        }
    }
}

// ---- tiny-ws fallback (not taken with 256MB ws) ----
__global__ __launch_bounds__(256) void zero_kernel(float4* __restrict__ o, int n4) {
    int i = blockIdx.x * 256 + threadIdx.x;
    if (i < n4) o[i] = make_float4(0.f, 0.f, 0.f, 0.f);
}
__global__ __launch_bounds__(512) void hist_atomic(const float* __restrict__ X,
                                                   float* __restrict__ out) {
    __shared__ float hflat[SLOTS];
    const int chunk = blockIdx.x % 12;
    const int b     = blockIdx.x / 12;
    for (int i = threadIdx.x; i < SLOTS; i += 512) hflat[i] = 0.0f;
    __syncthreads();
    const float* Xb = X + (size_t)b * 3 * NPIX;
    const int ppc = NPIX / 12;
    for (int n = chunk * ppc + threadIdx.x; n < (chunk + 1) * ppc; n += 512) {
        float r = Xb[n], g = Xb[NPIX + n], bl = Xb[2 * NPIX + n];
        DO_PIXEL(r, g, bl)
    }
    __syncthreads();
    float* ob = out + (size_t)b * SLOTS;
    for (int i = threadIdx.x; i < SLOTS; i += 512) {
        float v = hflat[i];
        if (v != 0.0f) unsafeAtomicAdd(&ob[i], v);
    }
}
__global__ __launch_bounds__(256) void finalize_kernel(float* __restrict__ out,
                                                       const float* __restrict__ C) {
    int idx = blockIdx.x * 256 + threadIdx.x;
    if (idx >= OUT_ELEMS) return;
    int ch = (idx / HB2) % 3;
    float scale = __fdiv_rn(C[ch], 22500.0f);
    out[idx] = __fmul_rn(__fsqrt_rn(out[idx]), scale);
}

extern "C" void kernel_launch(void* const* d_in, const int* in_sizes, int n_in,
                              void* d_out, int out_size, void* d_ws, size_t ws_size,
                              hipStream_t stream) {
    const float* X = (const float*)d_in[0];
    const float* C = (const float*)d_in[1];
    float* out = (float*)d_out;
    float* ws  = (float*)d_ws;

    size_t need = (size_t)NIMG * CH * SLOTS_PAD * sizeof(float);  // ~25.7 MB
    if (ws_size >= need) {
        hist_kernel<<<NIMG * CH, NT, 0, stream>>>(X, ws);
        reduce_kernel<<<NIMG, 1024, 0, stream>>>(ws, C, out);
    } else {
        int n4 = OUT_ELEMS / 4;
        zero_kernel<<<(n4 + 255) / 256, 256, 0, stream>>>((float4*)out, n4);
        hist_atomic<<<NIMG * 12, 512, 0, stream>>>(X, out);
        finalize_kernel<<<(OUT_ELEMS + 255) / 256, 256, 0, stream>>>(out, C);
    }
}